// Round 4
// baseline (6216.080 us; speedup 1.0000x reference)
//
#include <hip/hip_runtime.h>

#define BB 64
#define SS 1024
#define HH 512
#define NSPLIT 4   // CUs per chain
#define RPB 128    // output rows per block

typedef short short8 __attribute__((ext_vector_type(8)));
typedef float f32x4 __attribute__((ext_vector_type(4)));
typedef _Float16 h2 __attribute__((ext_vector_type(2)));

__device__ inline unsigned short f2bf(float f) {
  unsigned int u = __builtin_bit_cast(unsigned int, f);
  u += 0x7fffu + ((u >> 16) & 1u);   // round-to-nearest-even
  return (unsigned short)(u >> 16);
}

__device__ inline unsigned int pack_h2(float a, float b) {
  unsigned short ua = __builtin_bit_cast(unsigned short, (_Float16)a);
  unsigned short ub = __builtin_bit_cast(unsigned short, (_Float16)b);
  return (unsigned int)ua | ((unsigned int)ub << 16);
}

__device__ inline float dot2a(unsigned int w, unsigned int h, float acc) {
#if __has_builtin(__builtin_amdgcn_fdot2)
  return __builtin_amdgcn_fdot2(__builtin_bit_cast(h2, w),
                                __builtin_bit_cast(h2, h), acc, false);
#else
  h2 a = __builtin_bit_cast(h2, w);
  h2 b = __builtin_bit_cast(h2, h);
  return acc + (float)a[0] * (float)b[0] + (float)a[1] * (float)b[1];
#endif
}

// ---------------------------------------------------------------------------
// Phase 1: xt[m, n] = sum_k x[m,k] * W_ih[n,k] + b_ih[n].  Also resets the
// phase-2 arrive counters (block (0,0)) — runs every call, replay-safe.
// ---------------------------------------------------------------------------
__global__ __launch_bounds__(256) void xt_gemm(
    const float* __restrict__ x, const float* __restrict__ Wih,
    const float* __restrict__ bih, float* __restrict__ out,
    unsigned int* __restrict__ ws) {
  __shared__ unsigned short As[64][56];
  __shared__ unsigned short Bs[64][56];

  const int bn = blockIdx.x;  // 0..7
  const int bm = blockIdx.y;  // 0..1023
  const int t = threadIdx.x;
  if (bn == 0 && bm == 0 && t < 64) ws[t * 16] = 0;  // arrive[c] = 0

  const int wave = t >> 6, lane = t & 63;
  const int wm = wave >> 1, wn = wave & 1;
  const int m_base = bm * 64, n_base = bn * 64;
  const int sr = t >> 2;
  const int sc = (t & 3) * 8;

  f32x4 acc[2][2] = {};

  for (int k0 = 0; k0 < 512; k0 += 32) {
    __syncthreads();
    {
      const float* p = x + (size_t)(m_base + sr) * 512 + k0 + sc;
      float4 v0 = *(const float4*)p;
      float4 v1 = *(const float4*)(p + 4);
      short8 sa;
      sa[0] = (short)f2bf(v0.x); sa[1] = (short)f2bf(v0.y);
      sa[2] = (short)f2bf(v0.z); sa[3] = (short)f2bf(v0.w);
      sa[4] = (short)f2bf(v1.x); sa[5] = (short)f2bf(v1.y);
      sa[6] = (short)f2bf(v1.z); sa[7] = (short)f2bf(v1.w);
      *(short8*)&As[sr][sc] = sa;

      const float* q = Wih + (size_t)(n_base + sr) * 512 + k0 + sc;
      float4 w0 = *(const float4*)q;
      float4 w1 = *(const float4*)(q + 4);
      short8 sb;
      sb[0] = (short)f2bf(w0.x); sb[1] = (short)f2bf(w0.y);
      sb[2] = (short)f2bf(w0.z); sb[3] = (short)f2bf(w0.w);
      sb[4] = (short)f2bf(w1.x); sb[5] = (short)f2bf(w1.y);
      sb[6] = (short)f2bf(w1.z); sb[7] = (short)f2bf(w1.w);
      *(short8*)&Bs[sr][sc] = sb;
    }
    __syncthreads();

    const int kq = (lane >> 4) * 8;
    short8 a0 = *(const short8*)&As[wm * 32 + (lane & 15)][kq];
    short8 a1 = *(const short8*)&As[wm * 32 + 16 + (lane & 15)][kq];
    short8 b0 = *(const short8*)&Bs[wn * 32 + (lane & 15)][kq];
    short8 b1 = *(const short8*)&Bs[wn * 32 + 16 + (lane & 15)][kq];
    acc[0][0] = __builtin_amdgcn_mfma_f32_16x16x32_bf16(a0, b0, acc[0][0], 0, 0, 0);
    acc[0][1] = __builtin_amdgcn_mfma_f32_16x16x32_bf16(a0, b1, acc[0][1], 0, 0, 0);
    acc[1][0] = __builtin_amdgcn_mfma_f32_16x16x32_bf16(a1, b0, acc[1][0], 0, 0, 0);
    acc[1][1] = __builtin_amdgcn_mfma_f32_16x16x32_bf16(a1, b1, acc[1][1], 0, 0, 0);
  }

#pragma unroll
  for (int ni = 0; ni < 2; ++ni) {
    const int gcol = n_base + wn * 32 + ni * 16 + (lane & 15);
    const float bv = bih[gcol];
#pragma unroll
    for (int mi = 0; mi < 2; ++mi) {
#pragma unroll
      for (int j = 0; j < 4; ++j) {
        const int grow = m_base + wm * 32 + mi * 16 + (lane >> 4) * 4 + j;
        out[(size_t)grow * 512 + gcol] = acc[mi][ni][j] + bv;
      }
    }
  }
}

// ---------------------------------------------------------------------------
// Phase 2: 4 CUs per batch chain (256 blocks = whole machine).
// Block q of chain c owns rows [q*128, q*128+128). Thread t: row = t&127,
// k-span = (t>>7)*128 -> 64 weight dwords in VGPRs (fits 128-reg ceiling).
// Per step: dot -> LDS 4-way k-reduce -> tanh -> cross-CU h exchange via
// agent-scope stores + per-chain arrive counter (double-buffered in d_ws).
// ---------------------------------------------------------------------------
__global__
__attribute__((amdgpu_flat_work_group_size(512, 512)))
void rnn_scan(const float* __restrict__ Whh, const float* __restrict__ bhh,
              float* __restrict__ out, float* __restrict__ last,
              unsigned int* __restrict__ ws) {
  __shared__ struct {
    float part[NSPLIT * RPB];       // 2 KB  k-partials
    unsigned short hbuf[HH];        // 1 KB  current h (f16)
    unsigned short myh[RPB];        // 256 B own new-h chunk
    unsigned int pad[14592];        // ~58 KB -> LDS ~61.7 KB: <=2 blocks/CU
  } lds;

  unsigned int* arrive = ws;               // [64] stride 16 dwords
  unsigned int* hglob = ws + 1024;         // [64][2][256] dwords (h as f16x2)

  const int c = blockIdx.x & 63;           // chain
  const int q = blockIdx.x >> 6;           // block-in-chain: {c,c+64,..} same-XCD
  const int t = threadIdx.x;
  const int rl = t & 127;                  // local row
  const int kg = t >> 7;                   // 0..3 (wave-uniform: t>>7 == wave>>1)
  const int row = q * RPB + rl;

  // --- one-time weight load: W[row][kg*128 .. +128) as 64 f16x2 dwords ---
  unsigned int w[64];
  {
    const float* wr = Whh + (size_t)row * HH + kg * 128;
#pragma unroll
    for (int c4 = 0; c4 < 32; ++c4) {
      float4 f = ((const float4*)wr)[c4];
      w[2 * c4] = pack_h2(f.x, f.y);
      w[2 * c4 + 1] = pack_h2(f.z, f.w);
    }
  }
#pragma unroll
  for (int d = 0; d < 64; ++d) asm volatile("" : "+v"(w[d]));  // no remat/sink

  if (t < 256) ((unsigned int*)lds.hbuf)[t] = 0;  // h_0 = 0

  float* xb = out + (size_t)c * SS * HH + q * RPB;  // own column stripe
  float xt_cur = 0.f, bh = 0.f;
  if (t < RPB) { xt_cur = xb[t]; bh = bhh[q * RPB + t]; }
  const uint4* h4 = (const uint4*)lds.hbuf + kg * 16;
  __syncthreads();

  for (int step = 0; step < SS; ++step) {
    float xt_next = 0.f;
    if (t < RPB && step + 1 < SS) xt_next = xb[(size_t)(step + 1) * HH + t];

    // --- dot: a = W[row][k-span] . h[k-span] (64 dot2, weights in VGPRs) ---
    float a = 0.f;
#pragma unroll
    for (int i = 0; i < 16; ++i) {
      uint4 hv = h4[i];  // wave-uniform address -> broadcast
      a = dot2a(w[4 * i + 0], hv.x, a);
      a = dot2a(w[4 * i + 1], hv.y, a);
      a = dot2a(w[4 * i + 2], hv.z, a);
      a = dot2a(w[4 * i + 3], hv.w, a);
    }
    lds.part[kg * RPB + rl] = a;
    __syncthreads();

    // --- finalize own 128 rows ---
    if (t < RPB) {
      float y = xt_cur + bh + lds.part[t] + lds.part[RPB + t] +
                lds.part[2 * RPB + t] + lds.part[3 * RPB + t];
      float ht = tanhf(y);
      xb[(size_t)step * HH + t] = ht;  // fp32 output (overwrites xt in place)
      lds.myh[t] = __builtin_bit_cast(unsigned short, (_Float16)ht);
    }
    __syncthreads();

    // --- cross-CU exchange (double-buffered by step parity) ---
    const int par = (step + 1) & 1;
    unsigned int* buf = hglob + ((c << 1) | par) * 256;
    if (t < 64) {
      unsigned int v = ((const unsigned int*)lds.myh)[t];
      __hip_atomic_store(&buf[q * 64 + t], v, __ATOMIC_RELAXED,
                         __HIP_MEMORY_SCOPE_AGENT);
    }
    __syncthreads();  // per-wave vmcnt drain -> all stores at coherent point
    if (t == 0) {
      __hip_atomic_fetch_add(&arrive[c * 16], 1u, __ATOMIC_RELEASE,
                             __HIP_MEMORY_SCOPE_AGENT);
      const unsigned int target = 4u * (unsigned int)(step + 1);
      int polls = 0;
      while (__hip_atomic_load(&arrive[c * 16], __ATOMIC_ACQUIRE,
                               __HIP_MEMORY_SCOPE_AGENT) < target) {
        __builtin_amdgcn_s_sleep(1);
        if (++polls > (1 << 17)) break;  // insurance, never hit if correct
      }
    }
    __syncthreads();
    if (t < 256) {
      unsigned int v = __hip_atomic_load(&buf[t], __ATOMIC_RELAXED,
                                         __HIP_MEMORY_SCOPE_AGENT);
      ((unsigned int*)lds.hbuf)[t] = v;
    }
    xt_cur = xt_next;
    __syncthreads();
  }

  if (t < RPB) last[(size_t)c * HH + q * RPB + t] = xb[(size_t)(SS - 1) * HH + t];
}

extern "C" void kernel_launch(void* const* d_in, const int* in_sizes, int n_in,
                              void* d_out, int out_size, void* d_ws, size_t ws_size,
                              hipStream_t stream) {
  (void)in_sizes; (void)n_in; (void)ws_size; (void)out_size;
  const float* x   = (const float*)d_in[0];
  const float* Wih = (const float*)d_in[1];
  const float* bih = (const float*)d_in[2];
  const float* Whh = (const float*)d_in[3];
  const float* bhh = (const float*)d_in[4];
  float* out  = (float*)d_out;
  float* last = out + (size_t)BB * SS * HH;
  unsigned int* ws = (unsigned int*)d_ws;  // 4 KB flags + 128 KB h-exchange

  // Phase 1: input projection (also zeroes arrive counters each call)
  xt_gemm<<<dim3(8, 1024), 256, 0, stream>>>(x, Wih, bih, out, ws);

  // Phase 2: 64 chains x 4 CUs = 256 blocks
  rnn_scan<<<256, 512, 0, stream>>>(Whh, bhh, out, last, ws);
}

// Round 5
// 1613.577 us; speedup vs baseline: 3.8524x; 3.8524x over previous
//
#include <hip/hip_runtime.h>

#define BB 64
#define SS 1024
#define HH 512

typedef short short8 __attribute__((ext_vector_type(8)));
typedef float f32x4 __attribute__((ext_vector_type(4)));
typedef _Float16 h2 __attribute__((ext_vector_type(2)));

__device__ inline unsigned short f2bf(float f) {
  unsigned int u = __builtin_bit_cast(unsigned int, f);
  u += 0x7fffu + ((u >> 16) & 1u);   // round-to-nearest-even
  return (unsigned short)(u >> 16);
}

__device__ inline unsigned int pack_h2(float a, float b) {
  unsigned short ua = __builtin_bit_cast(unsigned short, (_Float16)a);
  unsigned short ub = __builtin_bit_cast(unsigned short, (_Float16)b);
  return (unsigned int)ua | ((unsigned int)ub << 16);
}

__device__ inline float dot2a(unsigned int w, unsigned int h, float acc) {
#if __has_builtin(__builtin_amdgcn_fdot2)
  return __builtin_amdgcn_fdot2(__builtin_bit_cast(h2, w),
                                __builtin_bit_cast(h2, h), acc, false);
#else
  h2 a = __builtin_bit_cast(h2, w);
  h2 b = __builtin_bit_cast(h2, h);
  return acc + (float)a[0] * (float)b[0] + (float)a[1] * (float)b[1];
#endif
}

// ---------------------------------------------------------------------------
// Phase 1: xt[m, n] = sum_k x[m,k] * W_ih[n,k] + b_ih[n],  m = b*S + s
// bf16 MFMA 16x16x32, BM=BN=64, BK=32, 256 threads (4 waves, 2x2 wave grid).
// Writes fp32 into d_out[0 : B*S*H]; phase 2 overwrites in place.
// ---------------------------------------------------------------------------
__global__ __launch_bounds__(256) void xt_gemm(
    const float* __restrict__ x, const float* __restrict__ Wih,
    const float* __restrict__ bih, float* __restrict__ out) {
  __shared__ unsigned short As[64][56];
  __shared__ unsigned short Bs[64][56];

  const int bn = blockIdx.x;  // 0..7
  const int bm = blockIdx.y;  // 0..1023
  const int t = threadIdx.x;
  const int wave = t >> 6, lane = t & 63;
  const int wm = wave >> 1, wn = wave & 1;
  const int m_base = bm * 64, n_base = bn * 64;
  const int sr = t >> 2;        // staging row 0..63
  const int sc = (t & 3) * 8;   // staging col chunk 0,8,16,24

  f32x4 acc[2][2] = {};

  for (int k0 = 0; k0 < 512; k0 += 32) {
    __syncthreads();
    {
      const float* p = x + (size_t)(m_base + sr) * 512 + k0 + sc;
      float4 v0 = *(const float4*)p;
      float4 v1 = *(const float4*)(p + 4);
      short8 sa;
      sa[0] = (short)f2bf(v0.x); sa[1] = (short)f2bf(v0.y);
      sa[2] = (short)f2bf(v0.z); sa[3] = (short)f2bf(v0.w);
      sa[4] = (short)f2bf(v1.x); sa[5] = (short)f2bf(v1.y);
      sa[6] = (short)f2bf(v1.z); sa[7] = (short)f2bf(v1.w);
      *(short8*)&As[sr][sc] = sa;

      const float* q = Wih + (size_t)(n_base + sr) * 512 + k0 + sc;
      float4 w0 = *(const float4*)q;
      float4 w1 = *(const float4*)(q + 4);
      short8 sb;
      sb[0] = (short)f2bf(w0.x); sb[1] = (short)f2bf(w0.y);
      sb[2] = (short)f2bf(w0.z); sb[3] = (short)f2bf(w0.w);
      sb[4] = (short)f2bf(w1.x); sb[5] = (short)f2bf(w1.y);
      sb[6] = (short)f2bf(w1.z); sb[7] = (short)f2bf(w1.w);
      *(short8*)&Bs[sr][sc] = sb;
    }
    __syncthreads();

    const int kq = (lane >> 4) * 8;  // k-chunk within BK
    short8 a0 = *(const short8*)&As[wm * 32 + (lane & 15)][kq];
    short8 a1 = *(const short8*)&As[wm * 32 + 16 + (lane & 15)][kq];
    short8 b0 = *(const short8*)&Bs[wn * 32 + (lane & 15)][kq];
    short8 b1 = *(const short8*)&Bs[wn * 32 + 16 + (lane & 15)][kq];
    acc[0][0] = __builtin_amdgcn_mfma_f32_16x16x32_bf16(a0, b0, acc[0][0], 0, 0, 0);
    acc[0][1] = __builtin_amdgcn_mfma_f32_16x16x32_bf16(a0, b1, acc[0][1], 0, 0, 0);
    acc[1][0] = __builtin_amdgcn_mfma_f32_16x16x32_bf16(a1, b0, acc[1][0], 0, 0, 0);
    acc[1][1] = __builtin_amdgcn_mfma_f32_16x16x32_bf16(a1, b1, acc[1][1], 0, 0, 0);
  }

  // C/D layout (m89-verified): col = lane&15 (N), row = (lane>>4)*4 + j (M)
#pragma unroll
  for (int ni = 0; ni < 2; ++ni) {
    const int gcol = n_base + wn * 32 + ni * 16 + (lane & 15);
    const float bv = bih[gcol];
#pragma unroll
    for (int mi = 0; mi < 2; ++mi) {
#pragma unroll
      for (int j = 0; j < 4; ++j) {
        const int grow = m_base + wm * 32 + mi * 16 + (lane >> 4) * 4 + j;
        out[(size_t)grow * 512 + gcol] = acc[mi][ni][j] + bv;
      }
    }
  }
}

// ---------------------------------------------------------------------------
// Phase 2: per-batch sequential scan, one WG (512 threads, 8 waves) per chain.
// Static 145 KB LDS -> 1 block/CU -> 2 waves/EU, so raising the VGPR budget
// is free: __launch_bounds__(512, 1) -> min 1 wave/EU -> 256-VGPR cap.
// Need: 192 weight dwords + ~30 working = ~222 regs.
// Thread t: kg = t>>6 (k-span 64, wave-uniform), hg = t&63.
// Outputs h = hg + 64*i, i=0..7: i=0..5 weights in VGPRs (asm-pinned),
// i=6..7 in LDS (128 KB). 8-way k-split -> LDS partial reduce.
// ---------------------------------------------------------------------------
__global__ __launch_bounds__(512, 1) void rnn_scan(
    const float* __restrict__ Whh, const float* __restrict__ bhh,
    float* __restrict__ out, float* __restrict__ last) {
  __shared__ uint4 wlds[16 * 512];        // 128 KB: W rows hg+384, hg+448
  __shared__ float part[8 * 512];         // 16 KB partials
  __shared__ unsigned short hbuf[512];    // 1 KB h state (f16)

  const int b = blockIdx.x;
  const int t = threadIdx.x;
  const int kg = t >> 6;        // 0..7, wave-uniform
  const int hg = t & 63;
  const int k0 = kg * 64;

  // --- one-time weight load: rows h = hg + 64*i, k in [k0, k0+64) ---
  unsigned int wreg[6][32];
#pragma unroll
  for (int i = 0; i < 6; ++i) {
    const float* wr = Whh + (size_t)(hg + 64 * i) * 512 + k0;
#pragma unroll
    for (int c4 = 0; c4 < 16; ++c4) {
      float4 f = ((const float4*)wr)[c4];
      wreg[i][c4 * 2]     = pack_h2(f.x, f.y);
      wreg[i][c4 * 2 + 1] = pack_h2(f.z, f.w);
    }
  }
  // pin weights: opaque definitions -> allocator cannot remat or sink the
  // load+convert chain into the step loop (the R1/R2 failure mode)
#pragma unroll
  for (int i = 0; i < 6; ++i) {
#pragma unroll
    for (int d = 0; d < 32; ++d) {
      asm volatile("" : "+v"(wreg[i][d]));
    }
  }

#pragma unroll
  for (int i = 6; i < 8; ++i) {
    const float* wr = Whh + (size_t)(hg + 64 * i) * 512 + k0;
#pragma unroll
    for (int c = 0; c < 8; ++c) {
      float4 f0 = ((const float4*)wr)[c * 2];
      float4 f1 = ((const float4*)wr)[c * 2 + 1];
      uint4 v;
      v.x = pack_h2(f0.x, f0.y); v.y = pack_h2(f0.z, f0.w);
      v.z = pack_h2(f1.x, f1.y); v.w = pack_h2(f1.z, f1.w);
      wlds[((i - 6) * 8 + c) * 512 + t] = v;
    }
  }
  if (t < 256) ((unsigned int*)hbuf)[t] = 0;  // h_0 = 0

  float* xt_row = out + (size_t)b * SS * HH;
  float xt_cur = xt_row[t];
  const float bh = bhh[t];
  const uint4* h4 = (const uint4*)hbuf + kg * 8;
  __syncthreads();

  for (int step = 0; step < SS; ++step) {
    // prefetch next xt (consumed next iteration; hides under dot phase)
    float xt_next = 0.f;
    if (step + 1 < SS) xt_next = xt_row[(size_t)(step + 1) * HH + t];

    // --- dot phase: a[i] = sum over k-span of W[hg+64i][k] * h[k] ---
    float a[8] = {0.f, 0.f, 0.f, 0.f, 0.f, 0.f, 0.f, 0.f};
#pragma unroll
    for (int c = 0; c < 8; ++c) {
      uint4 hv = h4[c];                      // broadcast (wave-uniform addr)
      uint4 w6 = wlds[c * 512 + t];          // conflict-free b128
      uint4 w7 = wlds[(8 + c) * 512 + t];
      a[0] = dot2a(wreg[0][4 * c + 0], hv.x, a[0]);
      a[0] = dot2a(wreg[0][4 * c + 1], hv.y, a[0]);
      a[0] = dot2a(wreg[0][4 * c + 2], hv.z, a[0]);
      a[0] = dot2a(wreg[0][4 * c + 3], hv.w, a[0]);
      a[1] = dot2a(wreg[1][4 * c + 0], hv.x, a[1]);
      a[1] = dot2a(wreg[1][4 * c + 1], hv.y, a[1]);
      a[1] = dot2a(wreg[1][4 * c + 2], hv.z, a[1]);
      a[1] = dot2a(wreg[1][4 * c + 3], hv.w, a[1]);
      a[2] = dot2a(wreg[2][4 * c + 0], hv.x, a[2]);
      a[2] = dot2a(wreg[2][4 * c + 1], hv.y, a[2]);
      a[2] = dot2a(wreg[2][4 * c + 2], hv.z, a[2]);
      a[2] = dot2a(wreg[2][4 * c + 3], hv.w, a[2]);
      a[3] = dot2a(wreg[3][4 * c + 0], hv.x, a[3]);
      a[3] = dot2a(wreg[3][4 * c + 1], hv.y, a[3]);
      a[3] = dot2a(wreg[3][4 * c + 2], hv.z, a[3]);
      a[3] = dot2a(wreg[3][4 * c + 3], hv.w, a[3]);
      a[4] = dot2a(wreg[4][4 * c + 0], hv.x, a[4]);
      a[4] = dot2a(wreg[4][4 * c + 1], hv.y, a[4]);
      a[4] = dot2a(wreg[4][4 * c + 2], hv.z, a[4]);
      a[4] = dot2a(wreg[4][4 * c + 3], hv.w, a[4]);
      a[5] = dot2a(wreg[5][4 * c + 0], hv.x, a[5]);
      a[5] = dot2a(wreg[5][4 * c + 1], hv.y, a[5]);
      a[5] = dot2a(wreg[5][4 * c + 2], hv.z, a[5]);
      a[5] = dot2a(wreg[5][4 * c + 3], hv.w, a[5]);
      a[6] = dot2a(w6.x, hv.x, a[6]);
      a[6] = dot2a(w6.y, hv.y, a[6]);
      a[6] = dot2a(w6.z, hv.z, a[6]);
      a[6] = dot2a(w6.w, hv.w, a[6]);
      a[7] = dot2a(w7.x, hv.x, a[7]);
      a[7] = dot2a(w7.y, hv.y, a[7]);
      a[7] = dot2a(w7.z, hv.z, a[7]);
      a[7] = dot2a(w7.w, hv.w, a[7]);
    }
    // partial store: within a wave lanes write consecutive dwords
#pragma unroll
    for (int i = 0; i < 8; ++i) part[kg * 512 + hg + 64 * i] = a[i];
    __syncthreads();

    // --- finalize: all 512 threads, h = t ---
    float y = xt_cur + bh;
#pragma unroll
    for (int g = 0; g < 8; ++g) y += part[g * 512 + t];
    float ht = tanhf(y);
    xt_row[(size_t)step * HH + t] = ht;  // overwrite xt with output h
    hbuf[t] = __builtin_bit_cast(unsigned short, (_Float16)ht);
    xt_cur = xt_next;
    __syncthreads();
  }

  // last = h_{S-1}: re-read the fp32 value just stored (L1/L2-hot)
  last[(size_t)b * HH + t] = xt_row[(size_t)(SS - 1) * HH + t];
}

extern "C" void kernel_launch(void* const* d_in, const int* in_sizes, int n_in,
                              void* d_out, int out_size, void* d_ws, size_t ws_size,
                              hipStream_t stream) {
  (void)in_sizes; (void)n_in; (void)d_ws; (void)ws_size; (void)out_size;
  const float* x   = (const float*)d_in[0];
  const float* Wih = (const float*)d_in[1];
  const float* bih = (const float*)d_in[2];
  const float* Whh = (const float*)d_in[3];
  const float* bhh = (const float*)d_in[4];
  float* out  = (float*)d_out;
  float* last = out + (size_t)BB * SS * HH;

  // Phase 1: input projection for all timesteps -> d_out (in-place xt buffer)
  xt_gemm<<<dim3(8, 1024), 256, 0, stream>>>(x, Wih, bih, out);

  // Phase 2: 64 sync-free per-batch chains, 145 KB static LDS each
  rnn_scan<<<64, 512, 0, stream>>>(Whh, bhh, out, last);
}